// Round 6
// baseline (523.624 us; speedup 1.0000x reference)
//
#include <hip/hip_runtime.h>

namespace {

constexpr int LMAX = 10;
constexpr double PI_D = 3.14159265358979323846;
constexpr double FACT[LMAX + 1] = {1., 1., 2., 6., 24., 120., 720., 5040., 40320., 362880., 3628800.};

constexpr double dfact(int n) {
    double r = 1.0;
    for (int i = 2; i <= n; ++i) r *= (double)i;
    return r;
}
constexpr double csqrt(double x) {
    if (x <= 0.0) return 0.0;
    double g = x > 1.0 ? x : 1.0;
    for (int i = 0; i < 100; ++i) g = 0.5 * (g + x / g);
    return g;
}

constexpr float coef_r(int l, int m, int p) {
    const int q = p - m, s = l - p - q;
    return (float)(1.0 / (FACT[p] * FACT[q] * FACT[s]));
}
constexpr float coef_i(int l, int m, int p) {
    const int   q = p - m;
    const float c = coef_r(l, m, p);
    return (q & 1) ? -c : c;  // (-1)^q folded (z2 = -conj(z1), exact in fp)
}

// Feature rows (M=64): u-pairs (p>=q, p+q<=10) minus u(5,5) -> rows 0..34;
// v-pairs (p>q, p+q<=10) minus v(10,0) -> rows 35..63. The two excluded
// features ride in spare B-columns 11/12, paired with row 0 (u(0,0) == 1).
constexpr bool u_excl(int p, int q) { return p == 5 && q == 5; }
constexpr bool v_excl(int p, int q) { return p == 10 && q == 0; }

constexpr int u_row(int p, int q) {
    int idx = 0;
    for (int pp = 0; pp <= LMAX; ++pp)
        for (int qq = 0; qq <= pp; ++qq) {
            if (pp + qq > LMAX) continue;
            if (u_excl(pp, qq)) continue;
            if (pp == p && qq == q) return idx;
            ++idx;
        }
    return -1;
}
constexpr int NU = 35;
constexpr int v_row(int p, int q) {
    int idx = 0;
    for (int pp = 1; pp <= LMAX; ++pp)
        for (int qq = 0; qq < pp; ++qq) {
            if (pp + qq > LMAX) continue;
            if (v_excl(pp, qq)) continue;
            if (pp == p && qq == q) return NU + idx;
            ++idx;
        }
    return -1;
}

// ---- phase-2 tables: out[lm] = oscl * sum_t cf * S[row][col] --------------
constexpr int MAXT = 6;
struct P2 {
    short row[121][MAXT];
    short col[121][MAXT];
    float cf[121][MAXT];
    short nt[121];
    short oidx[121];
    float oscl[121];
};
constexpr P2 make_p2() {
    P2  t{};
    int k = 0;
    for (int l = 0; l <= LMAX; ++l)
        for (int m = 0; m <= l; ++m) {
            int nt = 0;
            for (int p = m; 2 * p <= l + m; ++p) {
                const int q = p - m;
                if (u_excl(p, q)) { t.row[k][nt] = 0; t.col[k][nt] = 11; }
                else              { t.row[k][nt] = (short)u_row(p, q); t.col[k][nt] = (short)l; }
                t.cf[k][nt] = coef_r(l, m, p);
                ++nt;
            }
            t.nt[k] = (short)nt;
            const double scale = csqrt(dfact(l + m) * dfact(l - m)) * csqrt((2 * l + 1) / (4.0 * PI_D));
            if (m == 0) { t.oidx[k] = (short)(l * l + l); t.oscl[k] = (float)scale; }
            else {
                const double f = csqrt(2.0) * ((m & 1) ? -1.0 : 1.0);
                t.oidx[k] = (short)(l * l + l + m);
                t.oscl[k] = (float)(f * scale);
            }
            ++k;
        }
    for (int l = 1; l <= LMAX; ++l)
        for (int m = 1; m <= l; ++m) {
            int nt = 0;
            for (int p = m; 2 * p <= l + m; ++p) {
                const int q = p - m;
                if (v_excl(p, q)) { t.row[k][nt] = 0; t.col[k][nt] = 12; }
                else              { t.row[k][nt] = (short)v_row(p, q); t.col[k][nt] = (short)l; }
                t.cf[k][nt] = coef_i(l, m, p);
                ++nt;
            }
            t.nt[k] = (short)nt;
            const double scale = csqrt(dfact(l + m) * dfact(l - m)) * csqrt((2 * l + 1) / (4.0 * PI_D));
            const double f     = csqrt(2.0) * ((m & 1) ? -1.0 : 1.0);
            t.oidx[k] = (short)(l * l + l - m);
            t.oscl[k] = (float)(f * scale);
            ++k;
        }
    return t;
}
__constant__ P2 c_p2 = make_p2();

typedef __attribute__((ext_vector_type(8))) short bf16x8;
typedef __attribute__((ext_vector_type(4))) float f32x4;

// bf16 by truncation: error is multiplicative (~ -0.2% mean), propagates as a
// relative error of the sums -- well under the 2% harness threshold. Zero VALU
// cost beyond one lshr (often folded into ds_write_b16_d16_hi).
__device__ __forceinline__ unsigned short bh(float v) {
    return (unsigned short)(__float_as_uint(v) >> 16);
}

constexpr int NCOPY   = 16;    // partial-S copies in d_ws (contention control)
constexpr int KPAD    = 72;    // 64 k + 8 pad (16B-aligned rows, 2-way-max banks)
constexpr int WAVELDS = 64 * KPAD + 16 * KPAD;  // G[64][72] + B[16][72] shorts

}  // namespace

// Phase 1: per wave, per 64-point chunk: compute features, stage bf16 G (64
// rows = features x 64 cols = points) and B (16 rows = l-cols x 64 points) in
// a private LDS slice, then 2 K-steps x 4 M-tiles of mfma_f32_16x16x32_bf16
// accumulate S[64][16] in AGPRs. No __syncthreads anywhere: each wave touches
// only its own slice (same-wave LDS ordering via lgkmcnt).
__global__ __launch_bounds__(256) void sht_phase1(const float* __restrict__ pos,
                                                  float* __restrict__ ws, int n, int nwaves) {
    __shared__ alignas(16) unsigned short lds[4][WAVELDS];
    const int wv   = (int)threadIdx.x >> 6;
    const int lane = (int)threadIdx.x & 63;
    unsigned short* __restrict__ Gl = lds[wv];
    unsigned short* __restrict__ Bl = lds[wv] + 64 * KPAD;

    f32x4 acc[4];
#pragma unroll
    for (int t = 0; t < 4; ++t) acc[t] = f32x4{0.f, 0.f, 0.f, 0.f};

    const int wgid = (int)blockIdx.x * 4 + wv;
    const int nch  = (n + 63) >> 6;

    for (int c = wgid; c < nch; c += nwaves) {
        const int i = c * 64 + lane;
        float x = 0.f, y = 0.f, z0 = 0.f;
        if (i < n) {
            x  = pos[3 * i + 0];
            y  = pos[3 * i + 1];
            z0 = pos[3 * i + 2];
        }
        // (0,0,0) pads: B rows all 0 (w0=0) -> zero contribution.

        // Power table of z1 = (-x/2, -y/2) (matches ref's powcmplx)
        float zr[LMAX + 1], zi[LMAX + 1];
        zr[0] = 1.f;
        zi[0] = 0.f;
        const float ar = -0.5f * x, ai = -0.5f * y;
#pragma unroll
        for (int p = 1; p <= LMAX; ++p) {
            zr[p] = zr[p - 1] * ar - zi[p - 1] * ai;
            zi[p] = zi[p - 1] * ar + zr[p - 1] * ai;
        }
        float SR[LMAX + 1];
#pragma unroll
        for (int p = 0; p <= LMAX; ++p) SR[p] = zr[p] * zr[p];
        float SI[6];
        SI[0] = 0.f;
#pragma unroll
        for (int q = 1; q <= 5; ++q) SI[q] = zi[q] * zi[q];

        // u features: u(p,q) = SR[p]-SI[q]; u(p,0) = SR[p] (zi[0]=0, exact)
#pragma unroll
        for (int p = 0; p <= LMAX; ++p) {
#pragma unroll
            for (int q = 0; q <= p; ++q) {
                if (p + q <= LMAX && !u_excl(p, q)) {
                    const float val = (q == 0) ? SR[p] : (SR[p] - SI[q]);
                    Gl[u_row(p, q) * KPAD + lane] = bh(val);
                }
            }
        }
        // v features: v(p,q) = zi[p]*zr[q]-zr[p]*zi[q]; v(p,0) = zi[p]
#pragma unroll
        for (int p = 1; p <= LMAX; ++p) {
#pragma unroll
            for (int q = 0; q < p; ++q) {
                if (p + q <= LMAX && !v_excl(p, q)) {
                    const float val = (q == 0) ? zi[p] : (zi[p] * zr[q] - zr[p] * zi[q]);
                    Gl[v_row(p, q) * KPAD + lane] = bh(val);
                }
            }
        }

        // B columns: l=0..10 -> w0*r^l; 11 -> u(5,5)*w0r^10; 12 -> v(10,0)*w0r^10
        const float r2 = x * x + y * y + z0 * z0;
        const float r  = sqrtf(r2);
        float       wl = (r2 > 0.f) ? z0 : 0.f;  // x0 * mask
#pragma unroll
        for (int l = 0; l <= LMAX; ++l) {
            Bl[l * KPAD + lane] = bh(wl);
            if (l < LMAX) wl *= r;
        }
        Bl[11 * KPAD + lane] = bh((SR[5] - SI[5]) * wl);
        Bl[12 * KPAD + lane] = bh(zi[LMAX] * wl);
        // B rows 13..15 stale -> pollute only C cols 13..15 (never read).

        // S[64x16] += G(64xK) * B(Kx16), K=64 in 2 steps of 32.
        // A-frag: lane holds A[m=lane&15][k=(lane>>4)*8+j] -> contiguous row read.
        // B-frag (mirrored): B[k=(lane>>4)*8+j][n=lane&15] -> row n contiguous.
#pragma unroll
        for (int s = 0; s < 2; ++s) {
            const int    k0  = s * 32 + ((lane >> 4) << 3);
            const bf16x8 bfr = *(const bf16x8*)&Bl[(lane & 15) * KPAD + k0];
#pragma unroll
            for (int t = 0; t < 4; ++t) {
                const bf16x8 afr = *(const bf16x8*)&Gl[(t * 16 + (lane & 15)) * KPAD + k0];
                acc[t] = __builtin_amdgcn_mfma_f32_16x16x32_bf16(afr, bfr, acc[t], 0, 0, 0);
            }
        }
    }

    // Epilogue: C/D layout col=lane&15, row=(lane>>4)*4+reg (m89-verified).
    // One atomicAdd per held element into copy (wgid & 15): ~192 adds/address.
    float* __restrict__ Sc = ws + (size_t)(wgid & (NCOPY - 1)) * 1024;
#pragma unroll
    for (int t = 0; t < 4; ++t) {
#pragma unroll
        for (int e = 0; e < 4; ++e) {
            const int m  = t * 16 + ((lane >> 4) << 2) + e;
            const int nn = lane & 15;
            atomicAdd(&Sc[m * 16 + nn], acc[t][e]);
        }
    }
}

// Phase 2: fold 16 S-copies, then 121 outputs = tiny sparse matvec on S.
__global__ __launch_bounds__(256) void sht_phase2(const float* __restrict__ ws,
                                                  float* __restrict__ out) {
    __shared__ float S[1024];
    for (int c = (int)threadIdx.x; c < 1024; c += 256) {
        float s = 0.f;
#pragma unroll
        for (int k = 0; k < NCOPY; ++k) s += ws[k * 1024 + c];
        S[c] = s;
    }
    __syncthreads();
    const int k = (int)threadIdx.x;
    if (k < 121) {
        float     v  = 0.f;
        const int nt = c_p2.nt[k];
        for (int t = 0; t < nt; ++t)
            v = fmaf(c_p2.cf[k][t], S[(int)c_p2.row[k][t] * 16 + (int)c_p2.col[k][t]], v);
        out[c_p2.oidx[k]] = v * c_p2.oscl[k];
    }
}

extern "C" void kernel_launch(void* const* d_in, const int* in_sizes, int n_in,
                              void* d_out, int out_size, void* d_ws, size_t ws_size,
                              hipStream_t stream) {
    const float* pos = (const float*)d_in[0];
    float* out       = (float*)d_out;
    const int n      = in_sizes[0] / 3;  // (N,3) flat -> N points

    // Zero the S-partials (d_ws is re-poisoned before every timed launch).
    hipMemsetAsync(d_ws, 0, (size_t)NCOPY * 1024 * sizeof(float), stream);

    // 768 blocks x 4 waves: 3 blocks/CU (46 KB LDS each -> 138/160 KB), 3072
    // waves, ~10 chunks of 64 points per wave.
    const int blocks = 768;
    sht_phase1<<<blocks, 256, 0, stream>>>(pos, (float*)d_ws, n, blocks * 4);
    sht_phase2<<<1, 256, 0, stream>>>((const float*)d_ws, out);
}

// Round 7
// 209.563 us; speedup vs baseline: 2.4986x; 2.4986x over previous
//
#include <hip/hip_runtime.h>

namespace {

constexpr int LMAX  = 10;
constexpr int NPART = 4;
// Greedy-balanced partition of l into 4 parts by inner-term count:
// P0{10,3}, P1{9,4}, P2{8,5,1}, P3{7,6,2,0}
constexpr int PART_OF_L[LMAX + 1] = {3, 2, 3, 0, 1, 2, 3, 3, 2, 1, 0};
constexpr double PI_D = 3.14159265358979323846;

constexpr double FACT[LMAX + 1] = {1., 1., 2., 6., 24., 120., 720., 5040., 40320., 362880., 3628800.};

constexpr double dfact(int n) {
    double r = 1.0;
    for (int i = 2; i <= n; ++i) r *= (double)i;
    return r;
}
constexpr double csqrt(double x) {
    if (x <= 0.0) return 0.0;
    double g = x > 1.0 ? x : 1.0;
    for (int i = 0; i < 100; ++i) g = 0.5 * (g + x / g);
    return g;
}

constexpr float coef_r(int l, int m, int p) {
    const int q = p - m, s = l - p - q;
    return (float)(1.0 / (FACT[p] * FACT[q] * FACT[s]));
}
constexpr float coef_i(int l, int m, int p) {
    const int   q = p - m;
    const float c = coef_r(l, m, p);
    return (q & 1) ? -c : c;  // (-1)^q folded (z2 = -conj(z1), exact in fp)
}

// ---- per-part accumulator slot layout ------------------------------------
constexpr int slot_base(int part, int l) {
    int c = 0;
    for (int ll = 0; ll < l; ++ll)
        if (PART_OF_L[ll] == part) c += 2 * ll + 1;
    return c;
}
constexpr int nacc_part(int part) {
    int c = 0;
    for (int l = 0; l <= LMAX; ++l)
        if (PART_OF_L[l] == part) c += 2 * l + 1;
    return c;
}
constexpr int part_lmax(int part) {
    int mx = 0;
    for (int l = 0; l <= LMAX; ++l)
        if (PART_OF_L[l] == part) mx = l;
    return mx;
}
constexpr int slot_r(int part, int l, int m) { return slot_base(part, l) + m; }
constexpr int slot_i(int part, int l, int m) { return slot_base(part, l) + (l + 1) + (m - 1); }

constexpr int MAXNA = 34;

struct Tables {
    int   map[NPART][MAXNA];
    float scl[NPART][MAXNA];
};
constexpr Tables make_tables() {
    Tables t{};
    for (int part = 0; part < NPART; ++part) {
        for (int l = 0; l <= LMAX; ++l) {
            if (PART_OF_L[l] != part) continue;
            for (int m = 0; m <= l; ++m) {
                const int    k     = slot_r(part, l, m);
                const double scale = csqrt(dfact(l + m) * dfact(l - m)) * csqrt((2 * l + 1) / (4.0 * PI_D));
                if (m == 0) {
                    t.map[part][k] = l * l + l;
                    t.scl[part][k] = (float)scale;
                } else {
                    const double f = csqrt(2.0) * ((m & 1) ? -1.0 : 1.0);
                    t.map[part][k] = l * l + l + m;
                    t.scl[part][k] = (float)(f * scale);
                }
            }
            for (int m = 1; m <= l; ++m) {
                const int    k     = slot_i(part, l, m);
                const double scale = csqrt(dfact(l + m) * dfact(l - m)) * csqrt((2 * l + 1) / (4.0 * PI_D));
                const double f     = csqrt(2.0) * ((m & 1) ? -1.0 : 1.0);
                t.map[part][k] = l * l + l - m;
                t.scl[part][k] = (float)(f * scale);
            }
        }
    }
    return t;
}
__constant__ Tables c_tab = make_tables();

// Packed fp32: CDNA v_pk_fma_f32 / v_pk_mul_f32 / v_pk_add_f32 operate on
// VGPR pairs. <2 x float> IR selects to VOP3P; VOP3P has no literal encoding,
// which forces coefficient constants into registers hoisted OUT of the point
// loop (killing R2's per-point literal remat as a side effect), and sign
// flips become free neg_lo/neg_hi modifiers.
typedef __attribute__((ext_vector_type(2))) float f2;

__device__ __forceinline__ f2 mkf2(float s) {
    f2 r;
    r.x = s;
    r.y = s;
    return r;
}
__device__ __forceinline__ f2 fma2(f2 a, f2 b, f2 c) { return __builtin_elementwise_fma(a, b, c); }

}  // namespace

// Algebra (exact in fp): reference's z2 = (x/2,-y/2) = -conj(z1), z1 = (-x/2,-y/2).
//   zreal = z1r[p]^2 - z1i[q]^2
//   zimag = (-1)^q * (zi[p]zr[q] - zr[p]zi[q])   (sign folded into coef)
// Two points per eval: every table/square/term op is one packed instruction.
// Accumulators stay scalar (f2 halves are separate VGPRs -> .x/.y extract is
// free); fold costs 2 fma per pair = 1/pt, same as scalar R2.
template <int PART>
__device__ __forceinline__ void do_pair(f2 x, f2 y, f2 z0, float* acc) {
    constexpr int PL = part_lmax(PART);

    const f2 r2 = x * x + y * y + z0 * z0;
    f2       w0;
    w0.x = (r2.x > 0.f) ? z0.x : 0.f;  // x0 * mask
    w0.y = (r2.y > 0.f) ? z0.y : 0.f;

    // Powers of z1 = (-x/2, -y/2) (repeated complex multiply, matches ref)
    f2 zr[PL + 1], zi[PL + 1];
    zr[0] = mkf2(1.f);
    zi[0] = mkf2(0.f);
    const f2 ar = -0.5f * x, ai = -0.5f * y;
#pragma unroll
    for (int p = 1; p <= PL; ++p) {
        zr[p] = zr[p - 1] * ar - zi[p - 1] * ai;
        zi[p] = zi[p - 1] * ar + zr[p - 1] * ai;
    }
    f2 sr[PL + 1], si[PL / 2 + 1];
#pragma unroll
    for (int p = 0; p <= PL; ++p) sr[p] = zr[p] * zr[p];
#pragma unroll
    for (int q = 0; q <= PL / 2; ++q) si[q] = zi[q] * zi[q];

    f2 nrm;
    nrm.x = sqrtf(r2.x);
    nrm.y = sqrtf(r2.y);
    f2 rp[PL + 1];
    rp[0] = mkf2(1.f);
#pragma unroll
    for (int l = 1; l <= PL; ++l) rp[l] = rp[l - 1] * nrm;

#pragma unroll
    for (int l = 0; l <= LMAX; ++l) {
        if (PART_OF_L[l] != PART) continue;  // compile-time eliminated
        const f2 wrl = w0 * rp[l];
#pragma unroll
        for (int m = 0; m <= l; ++m) {
            f2 shr = mkf2(0.f), shi = mkf2(0.f);
#pragma unroll
            for (int p = m; 2 * p <= l + m; ++p) {
                const int q = p - m;
                shr = fma2(sr[p] - si[q], mkf2(coef_r(l, m, p)), shr);
                if (m > 0) {
                    const f2 v = zi[p] * zr[q] - zr[p] * zi[q];
                    shi = fma2(v, mkf2(coef_i(l, m, p)), shi);
                }
            }
            const int kr = slot_r(PART, l, m);
            acc[kr] = fmaf(wrl.x, shr.x, fmaf(wrl.y, shr.y, acc[kr]));
            if (m > 0) {
                const int ki = slot_i(PART, l, m);
                acc[ki] = fmaf(wrl.x, shi.x, fmaf(wrl.y, shi.y, acc[ki]));
            }
        }
    }
}

template <int PART>
__device__ __forceinline__ void sht_part(const float* __restrict__ pos, float* __restrict__ out,
                                         int n, int nblk) {
    constexpr int NA = nacc_part(PART);

    float acc[NA];
#pragma unroll
    for (int k = 0; k < NA; ++k) acc[k] = 0.f;

    const int bid    = (int)(blockIdx.x >> 2);
    const int tid    = bid * 256 + (int)threadIdx.x;
    const int stride = nblk * 256;
    const int nq     = (n + 3) >> 2;  // quads of 4 points = 2 packed pairs

    const float4* p4 = (const float4*)pos;

    for (int qd = tid; qd < nq; qd += stride) {
        float4 A, B, D;
        if (4 * qd + 3 < n) {  // 3 x dwordx4 = 4 points
            A = p4[3 * qd + 0];
            B = p4[3 * qd + 1];
            D = p4[3 * qd + 2];
        } else {  // boundary quad: per-point guarded; OOB -> (0,0,0) contributes 0
            float t[12];
#pragma unroll
            for (int j = 0; j < 4; ++j) {
                const int  pi = 4 * qd + j;
                const bool ok = pi < n;
                t[3 * j + 0] = ok ? pos[3 * pi + 0] : 0.f;
                t[3 * j + 1] = ok ? pos[3 * pi + 1] : 0.f;
                t[3 * j + 2] = ok ? pos[3 * pi + 2] : 0.f;
            }
            A = make_float4(t[0], t[1], t[2], t[3]);
            B = make_float4(t[4], t[5], t[6], t[7]);
            D = make_float4(t[8], t[9], t[10], t[11]);
        }
        // pair 0 = points 0,1; pair 1 = points 2,3
        f2 x0, y0, z0, x1, y1, z1;
        x0.x = A.x; x0.y = A.w;
        y0.x = A.y; y0.y = B.x;
        z0.x = A.z; z0.y = B.y;
        x1.x = B.z; x1.y = D.y;
        y1.x = B.w; y1.y = D.z;
        z1.x = D.x; z1.y = D.w;
        do_pair<PART>(x0, y0, z0, acc);
        do_pair<PART>(x1, y1, z1, acc);
    }

    // Wave (64-lane) shuffle reduction, then cross-wave via LDS.
    __shared__ float red[4][NA];
    const int lane = threadIdx.x & 63;
    const int wav  = threadIdx.x >> 6;
#pragma unroll
    for (int k = 0; k < NA; ++k) {
        float s = acc[k];
#pragma unroll
        for (int off = 32; off > 0; off >>= 1) s += __shfl_down(s, off, 64);
        if (lane == 0) red[wav][k] = s;
    }
    __syncthreads();
    if ((int)threadIdx.x < NA) {
        const int   k = (int)threadIdx.x;
        const float s = red[0][k] + red[1][k] + red[2][k] + red[3][k];
        atomicAdd(&out[c_tab.map[PART][k]], s * c_tab.scl[PART][k]);
    }
}

// (256,4): min 4 waves/EU -> VGPR hard cap 128. 1024 blocks x 4 waves = 4096
// waves = exactly 4/SIMD device-wide: one dispatch round, full residency.
__global__ __launch_bounds__(256, 4) void sht_kernel(const float* __restrict__ pos,
                                                     float* __restrict__ out, int n, int nblk) {
    // part = blockIdx & 3: with round-robin dispatch over 256 CUs (0 mod 4),
    // all resident blocks on one CU share a part -> I$ locality.
    switch (blockIdx.x & 3) {
        case 0: sht_part<0>(pos, out, n, nblk); break;
        case 1: sht_part<1>(pos, out, n, nblk); break;
        case 2: sht_part<2>(pos, out, n, nblk); break;
        default: sht_part<3>(pos, out, n, nblk); break;
    }
}

extern "C" void kernel_launch(void* const* d_in, const int* in_sizes, int n_in,
                              void* d_out, int out_size, void* d_ws, size_t ws_size,
                              hipStream_t stream) {
    const float* pos = (const float*)d_in[0];
    float* out       = (float*)d_out;
    const int n      = in_sizes[0] / 3;  // (N,3) flat -> N points

    // d_out is poisoned before every launch; we accumulate via atomics.
    hipMemsetAsync(d_out, 0, (size_t)out_size * sizeof(float), stream);

    const int threads       = 256;
    const int nblk_per_part = 256;                    // ~7.6 quads/thread
    const int blocks        = NPART * nblk_per_part;  // 1024
    sht_kernel<<<blocks, threads, 0, stream>>>(pos, out, n, nblk_per_part);
}